// Round 2
// baseline (244.474 us; speedup 1.0000x reference)
//
#include <hip/hip_runtime.h>
#include <cstdint>

typedef unsigned short u16;
typedef short v8s __attribute__((ext_vector_type(8)));
typedef float v4f __attribute__((ext_vector_type(4)));

static __device__ __forceinline__ u16 f2b(float f) {
    unsigned u = __float_as_uint(f);
    unsigned r = (u + 0x7fffu + ((u >> 16) & 1u)) >> 16;
    return (u16)r;
}

// ---------------------------------------------------------------------------
// Kernel A: x = feats@W1+b1; q=x@Wq; k=x@Wk; v=x@Wv (fp32 out). Also c4=[x,y,z,sq].
// ---------------------------------------------------------------------------
__global__ __launch_bounds__(256) void prep_kernel(
    const float* __restrict__ feats, const float* __restrict__ coords,
    const float* __restrict__ W1, const float* __restrict__ b1,
    const float* __restrict__ Wq, const float* __restrict__ Wk, const float* __restrict__ Wv,
    float* __restrict__ qb, float* __restrict__ kb, float* __restrict__ vb,
    float4* __restrict__ c4)
{
    __shared__ float sA[64 * 64];
    __shared__ float wB[64 * 64];
    __shared__ float xt[64 * 64];
    const int tid = threadIdx.x;
    const int gp0 = blockIdx.x * 64;

    if (tid < 64) {
        int p = gp0 + tid;
        float x = coords[p * 3 + 0];
        float y = coords[p * 3 + 1];
        float z = coords[p * 3 + 2];
        float sq = __fadd_rn(__fadd_rn(__fmul_rn(x, x), __fmul_rn(y, y)), __fmul_rn(z, z));
        c4[p] = make_float4(x, y, z, sq);
    }

    #pragma unroll
    for (int i = 0; i < 4; ++i) {
        int chunk = i * 256 + tid;          // 1024 chunks of 4 floats
        ((float4*)sA)[chunk] = ((const float4*)(feats + (size_t)gp0 * 64))[chunk];
        ((float4*)wB)[chunk] = ((const float4*)W1)[chunk];
    }
    __syncthreads();

    const int tx = tid & 15, py = tid >> 4;
    const int c0 = tx * 4, p0 = py * 4;

    {
        float acc[4][4] = {};
        for (int k = 0; k < 64; ++k) {
            float a_[4], w_[4];
            #pragma unroll
            for (int i = 0; i < 4; ++i) a_[i] = sA[(p0 + i) * 64 + k];
            #pragma unroll
            for (int j = 0; j < 4; ++j) w_[j] = wB[k * 64 + c0 + j];
            #pragma unroll
            for (int i = 0; i < 4; ++i)
                #pragma unroll
                for (int j = 0; j < 4; ++j)
                    acc[i][j] = fmaf(a_[i], w_[j], acc[i][j]);
        }
        float bs[4];
        #pragma unroll
        for (int j = 0; j < 4; ++j) bs[j] = b1[c0 + j];
        #pragma unroll
        for (int i = 0; i < 4; ++i)
            #pragma unroll
            for (int j = 0; j < 4; ++j)
                xt[(p0 + i) * 64 + c0 + j] = acc[i][j] + bs[j];
    }
    __syncthreads();

    const float* Ws[3] = {Wq, Wk, Wv};
    float* Os[3] = {qb, kb, vb};
    for (int mtx = 0; mtx < 3; ++mtx) {
        #pragma unroll
        for (int i = 0; i < 4; ++i) {
            int chunk = i * 256 + tid;
            ((float4*)wB)[chunk] = ((const float4*)Ws[mtx])[chunk];
        }
        __syncthreads();
        float acc[4][4] = {};
        for (int k = 0; k < 64; ++k) {
            float a_[4], w_[4];
            #pragma unroll
            for (int i = 0; i < 4; ++i) a_[i] = xt[(p0 + i) * 64 + k];
            #pragma unroll
            for (int j = 0; j < 4; ++j) w_[j] = wB[k * 64 + c0 + j];
            #pragma unroll
            for (int i = 0; i < 4; ++i)
                #pragma unroll
                for (int j = 0; j < 4; ++j)
                    acc[i][j] = fmaf(a_[i], w_[j], acc[i][j]);
        }
        #pragma unroll
        for (int i = 0; i < 4; ++i) {
            float4 st = make_float4(acc[i][0], acc[i][1], acc[i][2], acc[i][3]);
            *(float4*)(Os[mtx] + (size_t)(gp0 + p0 + i) * 64 + c0) = st;
        }
        __syncthreads();
    }
}

// ---------------------------------------------------------------------------
// Kernel A2: reshuffle Wp2/Wm1/Wm2 (fp32) into bf16 MFMA B-fragment order.
// ---------------------------------------------------------------------------
__global__ __launch_bounds__(256) void wprep_kernel(
    const float* __restrict__ Wp2, const float* __restrict__ Wm1,
    const float* __restrict__ Wm2, u16* __restrict__ wfrag)
{
    const float* srcs[3] = {Wp2, Wm1, Wm2};
    const float* W = srcs[blockIdx.x];
    for (int i = 0; i < 16; ++i) {
        int d = i * 256 + threadIdx.x;      // 0..4095
        int f = d >> 9;
        int lane = (d >> 3) & 63;
        int j = d & 7;
        int k = (f >> 2) * 32 + (lane >> 4) * 8 + j;
        int n = (f & 3) * 16 + (lane & 15);
        wfrag[blockIdx.x * 4096 + d] = f2b(W[k * 64 + n]);
    }
}

// ---------------------------------------------------------------------------
// Kernel B: exact KNN (top-16 by distance, stable tie-break by index).
// One wave per query; 4 queries per 256-thread block.
// ---------------------------------------------------------------------------
__global__ __launch_bounds__(256) void knn_kernel(
    const float4* __restrict__ c4, int* __restrict__ knn)
{
    __shared__ float lists[256 * 17];
    __shared__ unsigned long long keybuf[4][64];

    const int tid = threadIdx.x;
    const int lane = tid & 63, wv = tid >> 6;
    const int q = blockIdx.x * 4 + wv;
    const int b = q >> 12;
    const float4* cb = c4 + ((size_t)b << 12);
    const float4 cq = cb[q & 4095];
    const float sqi = cq.w;

    float dist[16];
    #pragma unroll
    for (int i = 0; i < 16; ++i) dist[i] = __builtin_inff();

    // Pass A: per-lane top-16 distances (branchless med3 insertion).
    for (int c = 0; c < 64; ++c) {
        float4 cj = cb[c * 64 + lane];
        float dot = __fadd_rn(__fadd_rn(__fmul_rn(cq.x, cj.x), __fmul_rn(cq.y, cj.y)),
                              __fmul_rn(cq.z, cj.z));
        float d = __fsub_rn(__fadd_rn(sqi, cj.w), __fmul_rn(2.0f, dot));
        #pragma unroll
        for (int i = 15; i > 0; --i)
            dist[i] = __builtin_amdgcn_fmed3f(dist[i - 1], d, dist[i]);
        dist[0] = fminf(dist[0], d);
    }

    #pragma unroll
    for (int i = 0; i < 16; ++i) lists[tid * 17 + i] = dist[i];
    __syncthreads();

    // Merge: 16th-smallest of the union via 16 extract-min steps.
    float h = lists[tid * 17 + 0];
    int ptr = 0;
    float d16 = 0.0f;
    for (int it = 0; it < 16; ++it) {
        float m = h;
        #pragma unroll
        for (int off = 32; off > 0; off >>= 1) m = fminf(m, __shfl_xor(m, off, 64));
        unsigned long long msk = __ballot(h == m);
        int first = __ffsll((unsigned long long)msk) - 1;
        if (lane == first) {
            ptr++;
            h = (ptr < 16) ? lists[tid * 17 + ptr] : __builtin_inff();
        }
        d16 = m;
    }

    // Pass B: collect all candidates with d <= d16 as (ordbits(d), idx) keys.
    int base = 0;
    for (int c = 0; c < 64; ++c) {
        float4 cj = cb[c * 64 + lane];
        float dot = __fadd_rn(__fadd_rn(__fmul_rn(cq.x, cj.x), __fmul_rn(cq.y, cj.y)),
                              __fmul_rn(cq.z, cj.z));
        float d = __fsub_rn(__fadd_rn(sqi, cj.w), __fmul_rn(2.0f, dot));
        bool sel = (d <= d16);
        unsigned long long msk = __ballot(sel);
        if (sel) {
            int pos = base + (int)__popcll(msk & ((1ull << lane) - 1ull));
            if (pos < 64) {
                unsigned u = __float_as_uint(d);
                unsigned ord = (u & 0x80000000u) ? ~u : (u | 0x80000000u);
                keybuf[wv][pos] = ((unsigned long long)ord << 32) | (unsigned)(c * 64 + lane);
            }
        }
        base += (int)__popcll(msk);
    }
    __syncthreads();

    int mcount = base < 64 ? base : 64;
    unsigned long long key = (lane < mcount) ? keybuf[wv][lane] : ~0ull;
    // 64-lane bitonic sort ascending on (d, idx).
    #pragma unroll
    for (int k = 2; k <= 64; k <<= 1) {
        #pragma unroll
        for (int j = k >> 1; j > 0; j >>= 1) {
            unsigned long long o = __shfl_xor(key, j, 64);
            bool up = ((lane & k) == 0);
            bool lower = ((lane & j) == 0);
            bool takemin = (lower == up);
            bool oless = (o < key);
            key = (takemin == oless) ? o : key;
        }
    }
    if (lane < 16) knn[q * 16 + lane] = (int)(unsigned)(key & 0xffffffffull);
}

// ---------------------------------------------------------------------------
// Kernel C: fused pos-enc / attention MLP / softmax / aggregation / out-proj.
// One wave per query; MFMA 16x16x32 bf16, M=16 neighbors.
// ---------------------------------------------------------------------------
__global__ __launch_bounds__(256, 2) void attn_kernel(
    const float* __restrict__ qb, const float* __restrict__ kb, const float* __restrict__ vb,
    const float4* __restrict__ c4, const int* __restrict__ knn,
    const u16* __restrict__ wfrag,
    const float* __restrict__ Wp1, const float* __restrict__ bp1, const float* __restrict__ bp2,
    const float* __restrict__ bm1, const float* __restrict__ bm2,
    const float* __restrict__ W2, const float* __restrict__ b2,
    const float* __restrict__ feats,
    float* __restrict__ out0, float* __restrict__ out_att)
{
    __shared__ float W2l[4096];
    __shared__ float posbuf[4][16 * 68];
    __shared__ float relbuf[4][16][4];
    __shared__ int idxbuf[4][16];
    __shared__ float obuf[4][64];

    const int tid = threadIdx.x;
    const int lane = tid & 63, wv = tid >> 6;
    const int q = blockIdx.x * 4 + wv;
    const int b = q >> 12;
    const int col = lane & 15, quad = lane >> 4;
    const int m = col;                       // neighbor row for A-operand

    #pragma unroll
    for (int i = 0; i < 16; ++i) W2l[i * 256 + tid] = W2[i * 256 + tid];

    if (lane < 16) {
        int jj = knn[q * 16 + lane] & 4095;  // clamp: correctness insurance
        idxbuf[wv][lane] = jj;
        float4 cj = c4[(b << 12) + jj];
        float4 cn = c4[q];
        relbuf[wv][lane][0] = cn.x - cj.x;
        relbuf[wv][lane][1] = cn.y - cj.y;
        relbuf[wv][lane][2] = cn.z - cj.z;
    }
    __syncthreads();

    const float r0 = relbuf[wv][m][0], r1 = relbuf[wv][m][1], r2 = relbuf[wv][m][2];

    // t = relu(rel @ Wp1 + bp1), built directly in A-fragment layout.
    v8s a0, a1;
    #pragma unroll
    for (int hh = 0; hh < 2; ++hh) {
        int tb = hh * 32 + quad * 8;
        #pragma unroll
        for (int j = 0; j < 8; ++j) {
            float t = bp1[tb + j];
            t = fmaf(r0, Wp1[0 * 64 + tb + j], t);
            t = fmaf(r1, Wp1[1 * 64 + tb + j], t);
            t = fmaf(r2, Wp1[2 * 64 + tb + j], t);
            t = fmaxf(t, 0.0f);
            if (hh == 0) a0[j] = (short)f2b(t); else a1[j] = (short)f2b(t);
        }
    }

    // pos = t @ Wp2 + bp2  (C-layout accumulators)
    v4f pos_c[4];
    #pragma unroll
    for (int nt = 0; nt < 4; ++nt) {
        float bias = bp2[nt * 16 + col];
        v4f acc = {bias, bias, bias, bias};
        v8s bf0 = *(const v8s*)(wfrag + (0 + nt) * 512 + lane * 8);
        v8s bf1 = *(const v8s*)(wfrag + (4 + nt) * 512 + lane * 8);
        acc = __builtin_amdgcn_mfma_f32_16x16x32_bf16(a0, bf0, acc, 0, 0, 0);
        acc = __builtin_amdgcn_mfma_f32_16x16x32_bf16(a1, bf1, acc, 0, 0, 0);
        pos_c[nt] = acc;
    }

    // C-layout -> LDS so we can rebuild A-layout for h.
    #pragma unroll
    for (int nt = 0; nt < 4; ++nt)
        #pragma unroll
        for (int r = 0; r < 4; ++r)
            posbuf[wv][(quad * 4 + r) * 68 + nt * 16 + col] = pos_c[nt][r];
    __syncthreads();

    // h = q - k + pos in A-layout.
    const int jm = idxbuf[wv][m];
    v8s ha0, ha1;
    #pragma unroll
    for (int hh = 0; hh < 2; ++hh) {
        int tb = hh * 32 + quad * 8;
        const float* qp = qb + (size_t)q * 64 + tb;
        const float* kp = kb + (size_t)((b << 12) + jm) * 64 + tb;
        const float* pp = &posbuf[wv][m * 68 + tb];
        #pragma unroll
        for (int j = 0; j < 8; ++j) {
            float hv = qp[j] - kp[j] + pp[j];
            if (hh == 0) ha0[j] = (short)f2b(hv); else ha1[j] = (short)f2b(hv);
        }
    }

    // g = relu(h @ Wm1 + bm1)
    v4f g_c[4];
    #pragma unroll
    for (int nt = 0; nt < 4; ++nt) {
        float bias = bm1[nt * 16 + col];
        v4f acc = {bias, bias, bias, bias};
        v8s bf0 = *(const v8s*)(wfrag + 4096 + (0 + nt) * 512 + lane * 8);
        v8s bf1 = *(const v8s*)(wfrag + 4096 + (4 + nt) * 512 + lane * 8);
        acc = __builtin_amdgcn_mfma_f32_16x16x32_bf16(ha0, bf0, acc, 0, 0, 0);
        acc = __builtin_amdgcn_mfma_f32_16x16x32_bf16(ha1, bf1, acc, 0, 0, 0);
        #pragma unroll
        for (int r = 0; r < 4; ++r) g_c[nt][r] = fmaxf(acc[r], 0.0f);
    }
    __syncthreads();        // done reading posbuf as pos
    #pragma unroll
    for (int nt = 0; nt < 4; ++nt)
        #pragma unroll
        for (int r = 0; r < 4; ++r)
            posbuf[wv][(quad * 4 + r) * 68 + nt * 16 + col] = g_c[nt][r];
    __syncthreads();

    v8s ga0, ga1;
    #pragma unroll
    for (int hh = 0; hh < 2; ++hh) {
        int tb = hh * 32 + quad * 8;
        const float* pp = &posbuf[wv][m * 68 + tb];
        #pragma unroll
        for (int j = 0; j < 8; ++j) {
            if (hh == 0) ga0[j] = (short)f2b(pp[j]); else ga1[j] = (short)f2b(pp[j]);
        }
    }

    // att = g @ Wm2 + bm2
    v4f att_c[4];
    #pragma unroll
    for (int nt = 0; nt < 4; ++nt) {
        float bias = bm2[nt * 16 + col];
        v4f acc = {bias, bias, bias, bias};
        v8s bf0 = *(const v8s*)(wfrag + 8192 + (0 + nt) * 512 + lane * 8);
        v8s bf1 = *(const v8s*)(wfrag + 8192 + (4 + nt) * 512 + lane * 8);
        acc = __builtin_amdgcn_mfma_f32_16x16x32_bf16(ga0, bf0, acc, 0, 0, 0);
        acc = __builtin_amdgcn_mfma_f32_16x16x32_bf16(ga1, bf1, acc, 0, 0, 0);
        att_c[nt] = acc;
    }

    // softmax over the 16 neighbors (rows) per channel (col): 4 regs x 4 quads.
    float att_sm[4][4];
    float o4[4];
    const size_t abase = (size_t)q * 1024;
    #pragma unroll
    for (int nt = 0; nt < 4; ++nt) {
        float s[4];
        #pragma unroll
        for (int r = 0; r < 4; ++r) s[r] = att_c[nt][r] * 0.125f;
        float mx = fmaxf(fmaxf(s[0], s[1]), fmaxf(s[2], s[3]));
        mx = fmaxf(mx, __shfl_xor(mx, 16, 64));
        mx = fmaxf(mx, __shfl_xor(mx, 32, 64));
        float e[4], sum = 0.0f;
        #pragma unroll
        for (int r = 0; r < 4; ++r) { e[r] = __expf(s[r] - mx); sum += e[r]; }
        sum += __shfl_xor(sum, 16, 64);
        sum += __shfl_xor(sum, 32, 64);
        float inv = 1.0f / sum;
        #pragma unroll
        for (int r = 0; r < 4; ++r) att_sm[nt][r] = e[r] * inv;

        float o = 0.0f;
        #pragma unroll
        for (int r = 0; r < 4; ++r) {
            int row = quad * 4 + r;
            out_att[abase + row * 64 + nt * 16 + col] = att_sm[nt][r];
            int jr = idxbuf[wv][row];
            float vvv = vb[(size_t)((b << 12) + jr) * 64 + nt * 16 + col];
            o = fmaf(att_sm[nt][r], vvv + pos_c[nt][r], o);
        }
        o += __shfl_xor(o, 16, 64);
        o += __shfl_xor(o, 32, 64);
        o4[nt] = o;
    }

    if (quad == 0) {
        #pragma unroll
        for (int nt = 0; nt < 4; ++nt) obuf[wv][nt * 16 + col] = o4[nt];
    }
    __syncthreads();

    // out = o @ W2 + b2 + features
    float acc = b2[lane] + feats[(size_t)q * 64 + lane];
    for (int t = 0; t < 64; ++t)
        acc = fmaf(obuf[wv][t], W2l[t * 64 + lane], acc);
    out0[(size_t)q * 64 + lane] = acc;
}

// ---------------------------------------------------------------------------
extern "C" void kernel_launch(void* const* d_in, const int* in_sizes, int n_in,
                              void* d_out, int out_size, void* d_ws, size_t ws_size,
                              hipStream_t stream)
{
    (void)in_sizes; (void)n_in; (void)out_size; (void)ws_size;
    const float* coords = (const float*)d_in[0];
    const float* feats  = (const float*)d_in[1];
    const float* W1  = (const float*)d_in[2];
    const float* b1  = (const float*)d_in[3];
    const float* Wq  = (const float*)d_in[4];
    const float* Wk  = (const float*)d_in[5];
    const float* Wv  = (const float*)d_in[6];
    const float* Wm1 = (const float*)d_in[7];
    const float* bm1 = (const float*)d_in[8];
    const float* Wm2 = (const float*)d_in[9];
    const float* bm2 = (const float*)d_in[10];
    const float* Wp1 = (const float*)d_in[11];
    const float* bp1 = (const float*)d_in[12];
    const float* Wp2 = (const float*)d_in[13];
    const float* bp2 = (const float*)d_in[14];
    const float* W2  = (const float*)d_in[15];
    const float* b2  = (const float*)d_in[16];

    char* ws = (char*)d_ws;
    float*  qb    = (float*)(ws);
    float*  kb    = (float*)(ws + (4u << 20));
    float*  vb    = (float*)(ws + (8u << 20));
    float4* c4    = (float4*)(ws + (12u << 20));
    int*    knn   = (int*)(ws + (12u << 20) + (256u << 10));
    u16*    wfrag = (u16*)(ws + (12u << 20) + (256u << 10) + (1u << 20));

    float* out0    = (float*)d_out;
    float* out_att = out0 + (size_t)4 * 4096 * 64;

    prep_kernel<<<256, 256, 0, stream>>>(feats, coords, W1, b1, Wq, Wk, Wv, qb, kb, vb, c4);
    wprep_kernel<<<3, 256, 0, stream>>>(Wp2, Wm1, Wm2, wfrag);
    knn_kernel<<<4096, 256, 0, stream>>>(c4, knn);
    attn_kernel<<<4096, 256, 0, stream>>>(qb, kb, vb, c4, knn, wfrag,
                                          Wp1, bp1, bp2, bm1, bm2, W2, b2, feats,
                                          out0, out_att);
}